// Round 1
// baseline (885.079 us; speedup 1.0000x reference)
//
#include <hip/hip_runtime.h>
#include <math.h>

#define N_NODES 100000
#define N_EDGES 1600000
#define N_GRAPHS 64
#define HID 64
#define LN_EPS 1e-5f

__device__ __forceinline__ float waveReduceSum(float v) {
#pragma unroll
    for (int off = 32; off > 0; off >>= 1)
        v += __shfl_xor(v, off, 64);
    return v;
}

// float atomic max via int/uint ordering trick (works for mixed signs, init -inf)
__device__ __forceinline__ void atomicMaxF(float* addr, float v) {
    if (v >= 0.0f)
        atomicMax((int*)addr, __float_as_int(v));
    else
        atomicMin((unsigned int*)addr, __float_as_uint(v));
}

// K0: per-node linear transforms + workspace init.
// one wave per node, lane = output channel.
__global__ __launch_bounds__(256) void k0_transform(
    const float* __restrict__ x,
    const float* __restrict__ Wl, const float* __restrict__ bl,
    const float* __restrict__ Wr, const float* __restrict__ br,
    float* __restrict__ xl, float* __restrict__ xr,
    float* __restrict__ m, float* __restrict__ denom,
    float* __restrict__ acc,
    float* __restrict__ gsum, float* __restrict__ gcnt,
    double* __restrict__ stats) {
    if (blockIdx.x == 0) {
        for (int i = threadIdx.x; i < N_GRAPHS * HID; i += blockDim.x) gsum[i] = 0.f;
        if (threadIdx.x < N_GRAPHS) gcnt[threadIdx.x] = 0.f;
        if (threadIdx.x < 2) stats[threadIdx.x] = 0.0;
    }
    int wid = (blockIdx.x * blockDim.x + threadIdx.x) >> 6;
    int lane = threadIdx.x & 63;
    if (wid >= N_NODES) return;
    int n = wid;
    float x0 = x[n * 4 + 0], x1 = x[n * 4 + 1], x2 = x[n * 4 + 2], x3 = x[n * 4 + 3];
    float vl = bl[lane] + x0 * Wl[0 * HID + lane] + x1 * Wl[1 * HID + lane] +
               x2 * Wl[2 * HID + lane] + x3 * Wl[3 * HID + lane];
    float vr = br[lane] + x0 * Wr[0 * HID + lane] + x1 * Wr[1 * HID + lane] +
               x2 * Wr[2 * HID + lane] + x3 * Wr[3 * HID + lane];
    xl[n * HID + lane] = vl;
    xr[n * HID + lane] = vr;
    acc[n * HID + lane] = 0.f;
    if (lane == 0) {
        m[n] = -INFINITY;
        denom[n] = 0.f;
    }
}

// K1: per-edge attention logit + segment max. one wave per edge.
__global__ __launch_bounds__(256) void k1_edge_scores(
    const int* __restrict__ ei,
    const float* __restrict__ xl, const float* __restrict__ xr,
    const float* __restrict__ att,
    float* __restrict__ e, float* __restrict__ m) {
    int eid = (blockIdx.x * blockDim.x + threadIdx.x) >> 6;
    int lane = threadIdx.x & 63;
    if (eid >= N_EDGES) return;
    int src = ei[eid];
    int dst = ei[N_EDGES + eid];
    float v = xl[src * HID + lane] + xr[dst * HID + lane];
    float lr = v > 0.f ? v : 0.2f * v;
    float s = waveReduceSum(lr * att[lane]);
    if (lane == 0) {
        e[eid] = s;
        atomicMaxF(&m[dst], s);
    }
}

// K2: per-edge exp + fused numerator/denominator accumulation.
__global__ __launch_bounds__(256) void k2_edge_agg(
    const int* __restrict__ ei,
    const float* __restrict__ xl,
    const float* __restrict__ e, const float* __restrict__ m,
    float* __restrict__ denom, float* __restrict__ acc) {
    int eid = (blockIdx.x * blockDim.x + threadIdx.x) >> 6;
    int lane = threadIdx.x & 63;
    if (eid >= N_EDGES) return;
    int src = ei[eid];
    int dst = ei[N_EDGES + eid];
    float ex = __expf(e[eid] - m[dst]);
    unsafeAtomicAdd(&acc[dst * HID + lane], ex * xl[src * HID + lane]);
    if (lane == 0) unsafeAtomicAdd(&denom[dst], ex);
}

// K3: node epilogue: normalize, bias, relu; accumulate global sum/sumsq and
// per-graph channel sums (batch is sorted -> contiguous chunks, few flushes).
__global__ __launch_bounds__(256) void k3_node_finish(
    const float* __restrict__ acc, const float* __restrict__ denom,
    const float* __restrict__ cb, const int* __restrict__ batch,
    float* __restrict__ gsum, float* __restrict__ gcnt,
    double* __restrict__ stats) {
    int wid = (blockIdx.x * blockDim.x + threadIdx.x) >> 6;
    int lane = threadIdx.x & 63;
    int nwaves = (gridDim.x * blockDim.x) >> 6;
    int chunk = (N_NODES + nwaves - 1) / nwaves;
    int n0 = wid * chunk;
    int n1 = min(n0 + chunk, N_NODES);
    float cbl = cb[lane];
    float lsum = 0.f, lsq = 0.f;
    float gacc = 0.f, lcnt = 0.f;
    int cur_g = -1;
    for (int n = n0; n < n1; ++n) {
        float d = denom[n];
        float val = acc[n * HID + lane];
        val = (d > 0.f ? val / d : 0.f) + cbl;
        val = fmaxf(val, 0.f);
        lsum += val;
        lsq += val * val;
        int g = batch[n];
        if (g != cur_g) {
            if (cur_g >= 0) {
                unsafeAtomicAdd(&gsum[cur_g * HID + lane], gacc);
                if (lane == 0) unsafeAtomicAdd(&gcnt[cur_g], lcnt);
            }
            cur_g = g;
            gacc = 0.f;
            lcnt = 0.f;
        }
        gacc += val;
        lcnt += 1.f;
    }
    if (cur_g >= 0) {
        unsafeAtomicAdd(&gsum[cur_g * HID + lane], gacc);
        if (lane == 0) unsafeAtomicAdd(&gcnt[cur_g], lcnt);
    }
    lsum = waveReduceSum(lsum);
    lsq = waveReduceSum(lsq);
    if (lane == 0) {
        unsafeAtomicAdd(&stats[0], (double)lsum);
        unsafeAtomicAdd(&stats[1], (double)lsq);
    }
}

// K4: per-graph head: pooled mean -> LN affine -> linear -> sigmoid.
__global__ __launch_bounds__(64) void k4_head(
    const float* __restrict__ gsum, const float* __restrict__ gcnt,
    const double* __restrict__ stats,
    const float* __restrict__ lnw, const float* __restrict__ lnb,
    const float* __restrict__ linw, const float* __restrict__ linb,
    float* __restrict__ y) {
    int g = blockIdx.x;
    int lane = threadIdx.x;
    double tot = (double)N_NODES * (double)HID;
    double mu = stats[0] / tot;
    double var = stats[1] / tot - mu * mu;
    float rs = rsqrtf((float)var + LN_EPS);
    float cnt = fmaxf(gcnt[g], 1.f);
    float pooled = (gsum[g * HID + lane] / cnt - (float)mu) * rs * lnw[lane] + lnb[lane];
    float t = waveReduceSum(pooled * linw[lane]);
    if (lane == 0) {
        float z = t + linb[0];
        y[g] = 1.f / (1.f + __expf(-z));
    }
}

extern "C" void kernel_launch(void* const* d_in, const int* in_sizes, int n_in,
                              void* d_out, int out_size, void* d_ws, size_t ws_size,
                              hipStream_t stream) {
    const float* x = (const float*)d_in[0];
    const int* ei = (const int*)d_in[1];
    const int* batch = (const int*)d_in[2];
    const float* Wl = (const float*)d_in[3];
    const float* bl = (const float*)d_in[4];
    const float* Wr = (const float*)d_in[5];
    const float* br = (const float*)d_in[6];
    const float* att = (const float*)d_in[7];
    const float* cb = (const float*)d_in[8];
    const float* lnw = (const float*)d_in[9];
    const float* lnb = (const float*)d_in[10];
    const float* linw = (const float*)d_in[11];
    const float* linb = (const float*)d_in[12];
    float* y = (float*)d_out;

    float* ws = (float*)d_ws;
    float* xl = ws;                               // N*HID
    float* xr = xl + (size_t)N_NODES * HID;       // N*HID
    float* acc = xr + (size_t)N_NODES * HID;      // N*HID
    float* e = acc + (size_t)N_NODES * HID;       // E
    float* m = e + (size_t)N_EDGES;               // N
    float* denom = m + N_NODES;                   // N
    float* gsum = denom + N_NODES;                // 64*64
    float* gcnt = gsum + N_GRAPHS * HID;          // 64
    double* stats = (double*)(gcnt + N_GRAPHS);   // 2 doubles (8B aligned)

    k0_transform<<<(N_NODES + 3) / 4, 256, 0, stream>>>(
        x, Wl, bl, Wr, br, xl, xr, m, denom, acc, gsum, gcnt, stats);
    k1_edge_scores<<<(N_EDGES + 3) / 4, 256, 0, stream>>>(ei, xl, xr, att, e, m);
    k2_edge_agg<<<(N_EDGES + 3) / 4, 256, 0, stream>>>(ei, xl, e, m, denom, acc);
    k3_node_finish<<<256, 256, 0, stream>>>(acc, denom, cb, batch, gsum, gcnt, stats);
    k4_head<<<N_GRAPHS, 64, 0, stream>>>(gsum, gcnt, stats, lnw, lnb, linw, linb, y);
}

// Round 2
// 578.852 us; speedup vs baseline: 1.5290x; 1.5290x over previous
//
#include <hip/hip_runtime.h>
#include <math.h>

#define N_NODES 100000
#define N_EDGES 1600000
#define N_GRAPHS 64
#define HID 64
#define LN_EPS 1e-5f
#define NB_SCAN ((N_NODES + 255) / 256)   // 391 scan blocks
#define ECAP 160                          // per-wave LDS stash for edge logits

__device__ __forceinline__ float waveReduceSum(float v) {
#pragma unroll
    for (int off = 32; off > 0; off >>= 1)
        v += __shfl_xor(v, off, 64);
    return v;
}

// K0: per-node linear transforms + all workspace init.
__global__ __launch_bounds__(256) void k0_transform(
    const float* __restrict__ x,
    const float* __restrict__ Wl, const float* __restrict__ bl,
    const float* __restrict__ Wr, const float* __restrict__ br,
    float* __restrict__ xl, float* __restrict__ xr,
    int* __restrict__ deg,
    float* __restrict__ gsum, float* __restrict__ gcnt,
    double* __restrict__ stats) {
    if (blockIdx.x == 0) {
        for (int i = threadIdx.x; i < N_GRAPHS * HID; i += blockDim.x) gsum[i] = 0.f;
        if (threadIdx.x < N_GRAPHS) gcnt[threadIdx.x] = 0.f;
        if (threadIdx.x < 2) stats[threadIdx.x] = 0.0;
    }
    int wid = (blockIdx.x * blockDim.x + threadIdx.x) >> 6;
    int lane = threadIdx.x & 63;
    if (wid >= N_NODES) return;
    int n = wid;
    float x0 = x[n * 4 + 0], x1 = x[n * 4 + 1], x2 = x[n * 4 + 2], x3 = x[n * 4 + 3];
    float vl = bl[lane] + x0 * Wl[0 * HID + lane] + x1 * Wl[1 * HID + lane] +
               x2 * Wl[2 * HID + lane] + x3 * Wl[3 * HID + lane];
    float vr = br[lane] + x0 * Wr[0 * HID + lane] + x1 * Wr[1 * HID + lane] +
               x2 * Wr[2 * HID + lane] + x3 * Wr[3 * HID + lane];
    xl[n * HID + lane] = vl;
    xr[n * HID + lane] = vr;
    if (lane == 0) deg[n] = 0;
}

// KA: degree histogram over destinations.
__global__ __launch_bounds__(256) void ka_hist(const int* __restrict__ ei,
                                               int* __restrict__ deg) {
    int i = blockIdx.x * blockDim.x + threadIdx.x;
    if (i < N_EDGES) atomicAdd(&deg[ei[N_EDGES + i]], 1);
}

// KB1: per-block exclusive scan of deg -> rowptr (block-local) + block totals.
__global__ __launch_bounds__(256) void kb1_scan(const int* __restrict__ deg,
                                                int* __restrict__ rowptr,
                                                int* __restrict__ bsum) {
    __shared__ int s[256];
    int i = blockIdx.x * 256 + threadIdx.x;
    int v = (i < N_NODES) ? deg[i] : 0;
    s[threadIdx.x] = v;
    __syncthreads();
#pragma unroll
    for (int off = 1; off < 256; off <<= 1) {
        int t = (threadIdx.x >= off) ? s[threadIdx.x - off] : 0;
        __syncthreads();
        s[threadIdx.x] += t;
        __syncthreads();
    }
    if (i < N_NODES) rowptr[i] = s[threadIdx.x] - v;  // exclusive
    if (threadIdx.x == 255) bsum[blockIdx.x] = s[255];
}

// KB2: single-block exclusive scan of the block totals (NB_SCAN=391 <= 512).
__global__ __launch_bounds__(512) void kb2_scan(int* __restrict__ bsum) {
    __shared__ int s[512];
    int v = (threadIdx.x < NB_SCAN) ? bsum[threadIdx.x] : 0;
    s[threadIdx.x] = v;
    __syncthreads();
#pragma unroll
    for (int off = 1; off < 512; off <<= 1) {
        int t = (threadIdx.x >= off) ? s[threadIdx.x - off] : 0;
        __syncthreads();
        s[threadIdx.x] += t;
        __syncthreads();
    }
    if (threadIdx.x < NB_SCAN) bsum[threadIdx.x] = s[threadIdx.x] - v;
}

// KB3: add block offsets; init cursor = rowptr.
__global__ __launch_bounds__(256) void kb3_fix(const int* __restrict__ bsum,
                                               int* __restrict__ rowptr,
                                               int* __restrict__ cursor) {
    int i = blockIdx.x * 256 + threadIdx.x;
    if (i < N_NODES) {
        int r = rowptr[i] + bsum[blockIdx.x];
        rowptr[i] = r;
        cursor[i] = r;
    }
    if (i == 0) rowptr[N_NODES] = N_EDGES;
}

// KC: scatter edge sources into dst-grouped order.
__global__ __launch_bounds__(256) void kc_scatter(const int* __restrict__ ei,
                                                  int* __restrict__ cursor,
                                                  int* __restrict__ esrc) {
    int i = blockIdx.x * blockDim.x + threadIdx.x;
    if (i >= N_EDGES) return;
    int src = ei[i];
    int dst = ei[N_EDGES + i];
    int slot = atomicAdd(&cursor[dst], 1);
    esrc[slot] = src;
}

// KD: one wave per destination node. Sweep 1: logits + max (LDS stash).
// Sweep 2: exp, weighted accumulate in registers, single coalesced store.
__global__ __launch_bounds__(256) void kd_node_agg(
    const int* __restrict__ rowptr, const int* __restrict__ esrc,
    const float* __restrict__ xl, const float* __restrict__ xr,
    const float* __restrict__ att, const float* __restrict__ cb,
    float* __restrict__ out) {
    __shared__ float eb[4][ECAP];
    int wid = (blockIdx.x * blockDim.x + threadIdx.x) >> 6;
    int lane = threadIdx.x & 63;
    int w = threadIdx.x >> 6;
    if (wid >= N_NODES) return;
    int n = wid;
    int beg = rowptr[n], end = rowptr[n + 1];
    float xr_d = xr[n * HID + lane];
    float attl = att[lane];
    float cbl = cb[lane];

    float m = -INFINITY;
    for (int j0 = beg; j0 < end; j0 += 64) {
        int cnt = min(64, end - j0);
        int srcv = (lane < cnt) ? esrc[j0 + lane] : 0;
        for (int j = 0; j < cnt; ++j) {
            int src = __shfl(srcv, j, 64);
            float v = xl[src * HID + lane] + xr_d;
            float lr = v > 0.f ? v : 0.2f * v;
            float e = waveReduceSum(lr * attl);  // all lanes hold total
            int idx = j0 - beg + j;
            if (idx < ECAP && lane == 0) eb[w][idx] = e;
            m = fmaxf(m, e);
        }
    }

    float num = 0.f, den = 0.f;
    for (int j0 = beg; j0 < end; j0 += 64) {
        int cnt = min(64, end - j0);
        int srcv = (lane < cnt) ? esrc[j0 + lane] : 0;
        for (int j = 0; j < cnt; ++j) {
            int idx = j0 - beg + j;
            int src = __shfl(srcv, j, 64);
            float e;
            if (idx < ECAP) {
                e = eb[w][idx];
            } else {  // overflow fallback (degree > ECAP): recompute
                float v = xl[src * HID + lane] + xr_d;
                float lr = v > 0.f ? v : 0.2f * v;
                e = waveReduceSum(lr * attl);
            }
            float ex = __expf(e - m);
            num += ex * xl[src * HID + lane];
            den += ex;
        }
    }
    float val = (den > 0.f ? num / den : 0.f) + cbl;
    out[n * HID + lane] = fmaxf(val, 0.f);
}

// K3: global LN stats + per-graph pooled sums (batch sorted -> few flushes).
__global__ __launch_bounds__(256) void k3_node_finish(
    const float* __restrict__ out, const int* __restrict__ batch,
    float* __restrict__ gsum, float* __restrict__ gcnt,
    double* __restrict__ stats) {
    int wid = (blockIdx.x * blockDim.x + threadIdx.x) >> 6;
    int lane = threadIdx.x & 63;
    int nwaves = (gridDim.x * blockDim.x) >> 6;
    int chunk = (N_NODES + nwaves - 1) / nwaves;
    int n0 = wid * chunk;
    int n1 = min(n0 + chunk, N_NODES);
    float lsum = 0.f, lsq = 0.f;
    float gacc = 0.f, lcnt = 0.f;
    int cur_g = -1;
    for (int n = n0; n < n1; ++n) {
        float val = out[n * HID + lane];
        lsum += val;
        lsq += val * val;
        int g = batch[n];
        if (g != cur_g) {
            if (cur_g >= 0) {
                unsafeAtomicAdd(&gsum[cur_g * HID + lane], gacc);
                if (lane == 0) unsafeAtomicAdd(&gcnt[cur_g], lcnt);
            }
            cur_g = g;
            gacc = 0.f;
            lcnt = 0.f;
        }
        gacc += val;
        lcnt += 1.f;
    }
    if (cur_g >= 0) {
        unsafeAtomicAdd(&gsum[cur_g * HID + lane], gacc);
        if (lane == 0) unsafeAtomicAdd(&gcnt[cur_g], lcnt);
    }
    lsum = waveReduceSum(lsum);
    lsq = waveReduceSum(lsq);
    if (lane == 0) {
        unsafeAtomicAdd(&stats[0], (double)lsum);
        unsafeAtomicAdd(&stats[1], (double)lsq);
    }
}

// K4: per-graph head.
__global__ __launch_bounds__(64) void k4_head(
    const float* __restrict__ gsum, const float* __restrict__ gcnt,
    const double* __restrict__ stats,
    const float* __restrict__ lnw, const float* __restrict__ lnb,
    const float* __restrict__ linw, const float* __restrict__ linb,
    float* __restrict__ y) {
    int g = blockIdx.x;
    int lane = threadIdx.x;
    double tot = (double)N_NODES * (double)HID;
    double mu = stats[0] / tot;
    double var = stats[1] / tot - mu * mu;
    float rs = rsqrtf((float)var + LN_EPS);
    float cnt = fmaxf(gcnt[g], 1.f);
    float pooled = (gsum[g * HID + lane] / cnt - (float)mu) * rs * lnw[lane] + lnb[lane];
    float t = waveReduceSum(pooled * linw[lane]);
    if (lane == 0) {
        float z = t + linb[0];
        y[g] = 1.f / (1.f + __expf(-z));
    }
}

extern "C" void kernel_launch(void* const* d_in, const int* in_sizes, int n_in,
                              void* d_out, int out_size, void* d_ws, size_t ws_size,
                              hipStream_t stream) {
    const float* x = (const float*)d_in[0];
    const int* ei = (const int*)d_in[1];
    const int* batch = (const int*)d_in[2];
    const float* Wl = (const float*)d_in[3];
    const float* bl = (const float*)d_in[4];
    const float* Wr = (const float*)d_in[5];
    const float* br = (const float*)d_in[6];
    const float* att = (const float*)d_in[7];
    const float* cb = (const float*)d_in[8];
    const float* lnw = (const float*)d_in[9];
    const float* lnb = (const float*)d_in[10];
    const float* linw = (const float*)d_in[11];
    const float* linb = (const float*)d_in[12];
    float* y = (float*)d_out;

    float* ws = (float*)d_ws;
    float* xl = ws;                               // N*HID
    float* xr = xl + (size_t)N_NODES * HID;       // N*HID
    float* out = xr + (size_t)N_NODES * HID;      // N*HID
    float* gsum = out + (size_t)N_NODES * HID;    // 64*64
    float* gcnt = gsum + N_GRAPHS * HID;          // 64
    double* stats = (double*)(gcnt + N_GRAPHS);   // 2 doubles
    int* rowptr = (int*)(stats + 2);              // N+1
    int* cursor = rowptr + (N_NODES + 1);         // N
    int* deg = cursor + N_NODES;                  // N
    int* bsum = deg + N_NODES;                    // NB_SCAN (<=512)
    int* esrc = bsum + 512;                       // E

    k0_transform<<<(N_NODES + 3) / 4, 256, 0, stream>>>(
        x, Wl, bl, Wr, br, xl, xr, deg, gsum, gcnt, stats);
    ka_hist<<<(N_EDGES + 255) / 256, 256, 0, stream>>>(ei, deg);
    kb1_scan<<<NB_SCAN, 256, 0, stream>>>(deg, rowptr, bsum);
    kb2_scan<<<1, 512, 0, stream>>>(bsum);
    kb3_fix<<<NB_SCAN, 256, 0, stream>>>(bsum, rowptr, cursor);
    kc_scatter<<<(N_EDGES + 255) / 256, 256, 0, stream>>>(ei, cursor, esrc);
    kd_node_agg<<<(N_NODES + 3) / 4, 256, 0, stream>>>(
        rowptr, esrc, xl, xr, att, cb, out);
    k3_node_finish<<<256, 256, 0, stream>>>(out, batch, gsum, gcnt, stats);
    k4_head<<<N_GRAPHS, 64, 0, stream>>>(gsum, gcnt, stats, lnw, lnb, linw, linb, y);
}

// Round 4
// 453.594 us; speedup vs baseline: 1.9513x; 1.2761x over previous
//
#include <hip/hip_runtime.h>
#include <math.h>

#define N_NODES 100000
#define N_EDGES 1600000
#define N_GRAPHS 64
#define HID 64
#define LN_EPS 1e-5f
#define NB_SCAN ((N_NODES + 255) / 256)   // 391 scan blocks
#define KD_BLOCKS 1024
#define KD_GROUPS (KD_BLOCKS * 16)        // 16 groups of 16 lanes per 256-thr block
#define KD_CHUNK ((N_NODES + KD_GROUPS - 1) / KD_GROUPS)  // 7 contiguous nodes/group

__device__ __forceinline__ float waveReduceSum(float v) {
#pragma unroll
    for (int off = 32; off > 0; off >>= 1)
        v += __shfl_xor(v, off, 64);
    return v;
}

__device__ __forceinline__ float groupReduceSum16(float v) {
#pragma unroll
    for (int off = 8; off > 0; off >>= 1)
        v += __shfl_xor(v, off, 64);
    return v;
}

__device__ __forceinline__ unsigned rne_bf16(float f) {
    unsigned u = __float_as_uint(f);
    return (u + 0x7fffu + ((u >> 16) & 1u)) >> 16;
}

// K0: per-node transforms. 16 lanes per node, 4 channels per lane.
// xr stored f32 (float4/lane), xl stored packed bf16 (uint2/lane). + ws init.
// Launch: one thread per (node, channel-group) = N_NODES*16 threads.
__global__ __launch_bounds__(256) void k0_transform(
    const float* __restrict__ x,
    const float* __restrict__ Wl, const float* __restrict__ bl,
    const float* __restrict__ Wr, const float* __restrict__ br,
    uint2* __restrict__ xlh, float4* __restrict__ xr4,
    int* __restrict__ deg,
    float* __restrict__ gsum, float* __restrict__ gcnt,
    double* __restrict__ stats) {
    if (blockIdx.x == 0) {
        for (int i = threadIdx.x; i < N_GRAPHS * HID; i += blockDim.x) gsum[i] = 0.f;
        if (threadIdx.x < N_GRAPHS) gcnt[threadIdx.x] = 0.f;
        if (threadIdx.x < 2) stats[threadIdx.x] = 0.0;
    }
    int t = blockIdx.x * blockDim.x + threadIdx.x;
    int n = t >> 4;
    int cg = t & 15;
    if (n >= N_NODES) return;
    float4 xv = ((const float4*)x)[n];
    float4 w0 = ((const float4*)Wl)[0 * 16 + cg];
    float4 w1 = ((const float4*)Wl)[1 * 16 + cg];
    float4 w2 = ((const float4*)Wl)[2 * 16 + cg];
    float4 w3 = ((const float4*)Wl)[3 * 16 + cg];
    float4 bv = ((const float4*)bl)[cg];
    float4 vl;
    vl.x = bv.x + xv.x * w0.x + xv.y * w1.x + xv.z * w2.x + xv.w * w3.x;
    vl.y = bv.y + xv.x * w0.y + xv.y * w1.y + xv.z * w2.y + xv.w * w3.y;
    vl.z = bv.z + xv.x * w0.z + xv.y * w1.z + xv.z * w2.z + xv.w * w3.z;
    vl.w = bv.w + xv.x * w0.w + xv.y * w1.w + xv.z * w2.w + xv.w * w3.w;
    w0 = ((const float4*)Wr)[0 * 16 + cg];
    w1 = ((const float4*)Wr)[1 * 16 + cg];
    w2 = ((const float4*)Wr)[2 * 16 + cg];
    w3 = ((const float4*)Wr)[3 * 16 + cg];
    bv = ((const float4*)br)[cg];
    float4 vr;
    vr.x = bv.x + xv.x * w0.x + xv.y * w1.x + xv.z * w2.x + xv.w * w3.x;
    vr.y = bv.y + xv.x * w0.y + xv.y * w1.y + xv.z * w2.y + xv.w * w3.y;
    vr.z = bv.z + xv.x * w0.z + xv.y * w1.z + xv.z * w2.z + xv.w * w3.z;
    vr.w = bv.w + xv.x * w0.w + xv.y * w1.w + xv.z * w2.w + xv.w * w3.w;
    xr4[n * 16 + cg] = vr;
    uint2 p;
    p.x = rne_bf16(vl.x) | (rne_bf16(vl.y) << 16);
    p.y = rne_bf16(vl.z) | (rne_bf16(vl.w) << 16);
    xlh[n * 16 + cg] = p;
    if (cg == 0) deg[n] = 0;
}

// KA: degree histogram over destinations.
__global__ __launch_bounds__(256) void ka_hist(const int* __restrict__ ei,
                                               int* __restrict__ deg) {
    int i = blockIdx.x * blockDim.x + threadIdx.x;
    if (i < N_EDGES) atomicAdd(&deg[ei[N_EDGES + i]], 1);
}

// KB1: per-block exclusive scan of deg -> rowptr (block-local) + block totals.
__global__ __launch_bounds__(256) void kb1_scan(const int* __restrict__ deg,
                                                int* __restrict__ rowptr,
                                                int* __restrict__ bsum) {
    __shared__ int s[256];
    int i = blockIdx.x * 256 + threadIdx.x;
    int v = (i < N_NODES) ? deg[i] : 0;
    s[threadIdx.x] = v;
    __syncthreads();
#pragma unroll
    for (int off = 1; off < 256; off <<= 1) {
        int t = (threadIdx.x >= off) ? s[threadIdx.x - off] : 0;
        __syncthreads();
        s[threadIdx.x] += t;
        __syncthreads();
    }
    if (i < N_NODES) rowptr[i] = s[threadIdx.x] - v;  // exclusive
    if (threadIdx.x == 255) bsum[blockIdx.x] = s[255];
}

// KB2: single-block exclusive scan of block totals (NB_SCAN=391 <= 512).
__global__ __launch_bounds__(512) void kb2_scan(int* __restrict__ bsum) {
    __shared__ int s[512];
    int v = (threadIdx.x < NB_SCAN) ? bsum[threadIdx.x] : 0;
    s[threadIdx.x] = v;
    __syncthreads();
#pragma unroll
    for (int off = 1; off < 512; off <<= 1) {
        int t = (threadIdx.x >= off) ? s[threadIdx.x - off] : 0;
        __syncthreads();
        s[threadIdx.x] += t;
        __syncthreads();
    }
    if (threadIdx.x < NB_SCAN) bsum[threadIdx.x] = s[threadIdx.x] - v;
}

// KB3: add block offsets; init cursor = rowptr.
__global__ __launch_bounds__(256) void kb3_fix(const int* __restrict__ bsum,
                                               int* __restrict__ rowptr,
                                               int* __restrict__ cursor) {
    int i = blockIdx.x * 256 + threadIdx.x;
    if (i < N_NODES) {
        int r = rowptr[i] + bsum[blockIdx.x];
        rowptr[i] = r;
        cursor[i] = r;
    }
    if (i == 0) rowptr[N_NODES] = N_EDGES;
}

// KC: scatter edge sources into dst-grouped order.
__global__ __launch_bounds__(256) void kc_scatter(const int* __restrict__ ei,
                                                  int* __restrict__ cursor,
                                                  int* __restrict__ esrc) {
    int i = blockIdx.x * blockDim.x + threadIdx.x;
    if (i >= N_EDGES) return;
    int src = ei[i];
    int dst = ei[N_EDGES + i];
    int slot = atomicAdd(&cursor[dst], 1);
    esrc[slot] = src;
}

// KD: fused node aggregation + LN stats + graph pooling.
// 16-lane group per node, 4 ch/lane. Single sweep, no segment-max
// (logits are O(+-5): exp(e)/sum(exp(e)) is exactly the reference softmax).
__global__ __launch_bounds__(256) void kd_node_agg(
    const int* __restrict__ rowptr, const int* __restrict__ esrc,
    const uint2* __restrict__ xlh, const float4* __restrict__ xr4,
    const float* __restrict__ att, const float* __restrict__ cb,
    const int* __restrict__ batch,
    float* __restrict__ gsum, float* __restrict__ gcnt,
    double* __restrict__ stats) {
    __shared__ float sS[16], sQ[16];
    int gib = threadIdx.x >> 4;           // group-in-block 0..15
    int cg = threadIdx.x & 15;
    int gid = blockIdx.x * 16 + gib;      // global group id
    int n0 = gid * KD_CHUNK;
    int n1 = min(n0 + KD_CHUNK, N_NODES);

    float4 av = ((const float4*)att)[cg];
    float4 cv = ((const float4*)cb)[cg];

    float lsum = 0.f, lsq = 0.f;
    float gacc0 = 0.f, gacc1 = 0.f, gacc2 = 0.f, gacc3 = 0.f;
    float runcnt = 0.f;
    int cur_g = -1;

    for (int n = n0; n < n1; ++n) {
        int beg = rowptr[n], end = rowptr[n + 1];
        float4 xr = xr4[n * 16 + cg];
        float num0 = 0.f, num1 = 0.f, num2 = 0.f, num3 = 0.f, den = 0.f;
        // software-pipelined gather: next edge's row loads under current compute
        int src = (beg < end) ? esrc[beg] : 0;
        uint2 p = (beg < end) ? xlh[src * 16 + cg] : make_uint2(0, 0);
        for (int j = beg; j < end; ++j) {
            uint2 pc = p;
            if (j + 1 < end) {
                int sn = esrc[j + 1];
                p = xlh[sn * 16 + cg];
            }
            float f0 = __uint_as_float(pc.x << 16);
            float f1 = __uint_as_float(pc.x & 0xffff0000u);
            float f2 = __uint_as_float(pc.y << 16);
            float f3 = __uint_as_float(pc.y & 0xffff0000u);
            float h0 = f0 + xr.x, h1 = f1 + xr.y, h2 = f2 + xr.z, h3 = f3 + xr.w;
            float l0 = fmaxf(h0, 0.f) + 0.2f * fminf(h0, 0.f);
            float l1 = fmaxf(h1, 0.f) + 0.2f * fminf(h1, 0.f);
            float l2 = fmaxf(h2, 0.f) + 0.2f * fminf(h2, 0.f);
            float l3 = fmaxf(h3, 0.f) + 0.2f * fminf(h3, 0.f);
            float part = l0 * av.x + l1 * av.y + l2 * av.z + l3 * av.w;
            float e = groupReduceSum16(part);
            float ex = __expf(e);
            den += ex;
            num0 += ex * f0; num1 += ex * f1; num2 += ex * f2; num3 += ex * f3;
        }
        float inv = (den > 0.f) ? (1.f / den) : 0.f;
        float v0 = fmaxf(num0 * inv + cv.x, 0.f);
        float v1 = fmaxf(num1 * inv + cv.y, 0.f);
        float v2 = fmaxf(num2 * inv + cv.z, 0.f);
        float v3 = fmaxf(num3 * inv + cv.w, 0.f);
        lsum += v0 + v1 + v2 + v3;
        lsq += v0 * v0 + v1 * v1 + v2 * v2 + v3 * v3;
        int g = batch[n];
        if (g != cur_g) {
            if (cur_g >= 0) {
                unsafeAtomicAdd(&gsum[cur_g * HID + cg * 4 + 0], gacc0);
                unsafeAtomicAdd(&gsum[cur_g * HID + cg * 4 + 1], gacc1);
                unsafeAtomicAdd(&gsum[cur_g * HID + cg * 4 + 2], gacc2);
                unsafeAtomicAdd(&gsum[cur_g * HID + cg * 4 + 3], gacc3);
                if (cg == 0) unsafeAtomicAdd(&gcnt[cur_g], runcnt);
            }
            cur_g = g;
            gacc0 = gacc1 = gacc2 = gacc3 = 0.f;
            runcnt = 0.f;
        }
        gacc0 += v0; gacc1 += v1; gacc2 += v2; gacc3 += v3;
        runcnt += 1.f;
    }
    if (cur_g >= 0) {
        unsafeAtomicAdd(&gsum[cur_g * HID + cg * 4 + 0], gacc0);
        unsafeAtomicAdd(&gsum[cur_g * HID + cg * 4 + 1], gacc1);
        unsafeAtomicAdd(&gsum[cur_g * HID + cg * 4 + 2], gacc2);
        unsafeAtomicAdd(&gsum[cur_g * HID + cg * 4 + 3], gacc3);
        if (cg == 0) unsafeAtomicAdd(&gcnt[cur_g], runcnt);
    }
    // block-level LN-stats reduce -> 2 f64 atomics per block
    lsum = groupReduceSum16(lsum);
    lsq = groupReduceSum16(lsq);
    if (cg == 0) { sS[gib] = lsum; sQ[gib] = lsq; }
    __syncthreads();
    if (threadIdx.x == 0) {
        double ds = 0.0, dq = 0.0;
#pragma unroll
        for (int i = 0; i < 16; ++i) { ds += (double)sS[i]; dq += (double)sQ[i]; }
        unsafeAtomicAdd(&stats[0], ds);
        unsafeAtomicAdd(&stats[1], dq);
    }
}

// K4: per-graph head.
__global__ __launch_bounds__(64) void k4_head(
    const float* __restrict__ gsum, const float* __restrict__ gcnt,
    const double* __restrict__ stats,
    const float* __restrict__ lnw, const float* __restrict__ lnb,
    const float* __restrict__ linw, const float* __restrict__ linb,
    float* __restrict__ y) {
    int g = blockIdx.x;
    int lane = threadIdx.x;
    double tot = (double)N_NODES * (double)HID;
    double mu = stats[0] / tot;
    double var = stats[1] / tot - mu * mu;
    float rs = rsqrtf((float)var + LN_EPS);
    float cnt = fmaxf(gcnt[g], 1.f);
    float pooled = (gsum[g * HID + lane] / cnt - (float)mu) * rs * lnw[lane] + lnb[lane];
    float t = waveReduceSum(pooled * linw[lane]);
    if (lane == 0) {
        float z = t + linb[0];
        y[g] = 1.f / (1.f + __expf(-z));
    }
}

extern "C" void kernel_launch(void* const* d_in, const int* in_sizes, int n_in,
                              void* d_out, int out_size, void* d_ws, size_t ws_size,
                              hipStream_t stream) {
    const float* x = (const float*)d_in[0];
    const int* ei = (const int*)d_in[1];
    const int* batch = (const int*)d_in[2];
    const float* Wl = (const float*)d_in[3];
    const float* bl = (const float*)d_in[4];
    const float* Wr = (const float*)d_in[5];
    const float* br = (const float*)d_in[6];
    const float* att = (const float*)d_in[7];
    const float* cb = (const float*)d_in[8];
    const float* lnw = (const float*)d_in[9];
    const float* lnb = (const float*)d_in[10];
    const float* linw = (const float*)d_in[11];
    const float* linb = (const float*)d_in[12];
    float* y = (float*)d_out;

    char* ws = (char*)d_ws;
    float4* xr4 = (float4*)ws;                                   // N*16 float4
    uint2* xlh = (uint2*)(ws + (size_t)N_NODES * 16 * 16);       // N*16 uint2
    float* gsum = (float*)((char*)xlh + (size_t)N_NODES * 16 * 8);
    float* gcnt = gsum + N_GRAPHS * HID;
    double* stats = (double*)(gcnt + N_GRAPHS);
    int* rowptr = (int*)(stats + 2);
    int* cursor = rowptr + (N_NODES + 1);
    int* deg = cursor + N_NODES;
    int* bsum = deg + N_NODES;
    int* esrc = bsum + 512;

    k0_transform<<<(N_NODES * 16 + 255) / 256, 256, 0, stream>>>(
        x, Wl, bl, Wr, br, xlh, xr4, deg, gsum, gcnt, stats);
    ka_hist<<<(N_EDGES + 255) / 256, 256, 0, stream>>>(ei, deg);
    kb1_scan<<<NB_SCAN, 256, 0, stream>>>(deg, rowptr, bsum);
    kb2_scan<<<1, 512, 0, stream>>>(bsum);
    kb3_fix<<<NB_SCAN, 256, 0, stream>>>(bsum, rowptr, cursor);
    kc_scatter<<<(N_EDGES + 255) / 256, 256, 0, stream>>>(ei, cursor, esrc);
    kd_node_agg<<<KD_BLOCKS, 256, 0, stream>>>(
        rowptr, esrc, xlh, xr4, att, cb, batch, gsum, gcnt, stats);
    k4_head<<<N_GRAPHS, 64, 0, stream>>>(gsum, gcnt, stats, lnw, lnb, linw, linb, y);
}

// Round 5
// 402.161 us; speedup vs baseline: 2.2008x; 1.1279x over previous
//
#include <hip/hip_runtime.h>
#include <math.h>

#define N_NODES 100000
#define N_EDGES 1600000
#define N_GRAPHS 64
#define HID 64
#define LN_EPS 1e-5f
#define NB_SCAN ((N_NODES + 255) / 256)   // 391 scan blocks
#define KD_BLOCKS 2048
#define KD_WAVES (KD_BLOCKS * 4)          // 8192 waves, one node-chunk per wave
#define KD_CHUNK ((N_NODES + KD_WAVES - 1) / KD_WAVES)  // 13 contiguous nodes/wave

__device__ __forceinline__ float waveReduceSum(float v) {
#pragma unroll
    for (int off = 32; off > 0; off >>= 1)
        v += __shfl_xor(v, off, 64);
    return v;
}

__device__ __forceinline__ float groupReduceSum16(float v) {
#pragma unroll
    for (int off = 8; off > 0; off >>= 1)
        v += __shfl_xor(v, off, 64);
    return v;
}

__device__ __forceinline__ unsigned rne_bf16(float f) {
    unsigned u = __float_as_uint(f);
    return (u + 0x7fffu + ((u >> 16) & 1u)) >> 16;
}

// K0: per-node transforms. One thread per (node, channel-group).
// xr stored f32 (float4/lane), xl stored packed bf16 (uint2/lane). + ws init.
__global__ __launch_bounds__(256) void k0_transform(
    const float* __restrict__ x,
    const float* __restrict__ Wl, const float* __restrict__ bl,
    const float* __restrict__ Wr, const float* __restrict__ br,
    uint2* __restrict__ xlh, float4* __restrict__ xr4,
    int* __restrict__ deg,
    float* __restrict__ gsum, float* __restrict__ gcnt,
    double* __restrict__ stats) {
    if (blockIdx.x == 0) {
        for (int i = threadIdx.x; i < N_GRAPHS * HID; i += blockDim.x) gsum[i] = 0.f;
        if (threadIdx.x < N_GRAPHS) gcnt[threadIdx.x] = 0.f;
        if (threadIdx.x < 2) stats[threadIdx.x] = 0.0;
    }
    int t = blockIdx.x * blockDim.x + threadIdx.x;
    int n = t >> 4;
    int cg = t & 15;
    if (n >= N_NODES) return;
    float4 xv = ((const float4*)x)[n];
    float4 w0 = ((const float4*)Wl)[0 * 16 + cg];
    float4 w1 = ((const float4*)Wl)[1 * 16 + cg];
    float4 w2 = ((const float4*)Wl)[2 * 16 + cg];
    float4 w3 = ((const float4*)Wl)[3 * 16 + cg];
    float4 bv = ((const float4*)bl)[cg];
    float4 vl;
    vl.x = bv.x + xv.x * w0.x + xv.y * w1.x + xv.z * w2.x + xv.w * w3.x;
    vl.y = bv.y + xv.x * w0.y + xv.y * w1.y + xv.z * w2.y + xv.w * w3.y;
    vl.z = bv.z + xv.x * w0.z + xv.y * w1.z + xv.z * w2.z + xv.w * w3.z;
    vl.w = bv.w + xv.x * w0.w + xv.y * w1.w + xv.z * w2.w + xv.w * w3.w;
    w0 = ((const float4*)Wr)[0 * 16 + cg];
    w1 = ((const float4*)Wr)[1 * 16 + cg];
    w2 = ((const float4*)Wr)[2 * 16 + cg];
    w3 = ((const float4*)Wr)[3 * 16 + cg];
    bv = ((const float4*)br)[cg];
    float4 vr;
    vr.x = bv.x + xv.x * w0.x + xv.y * w1.x + xv.z * w2.x + xv.w * w3.x;
    vr.y = bv.y + xv.x * w0.y + xv.y * w1.y + xv.z * w2.y + xv.w * w3.y;
    vr.z = bv.z + xv.x * w0.z + xv.y * w1.z + xv.z * w2.z + xv.w * w3.z;
    vr.w = bv.w + xv.x * w0.w + xv.y * w1.w + xv.z * w2.w + xv.w * w3.w;
    xr4[n * 16 + cg] = vr;
    uint2 p;
    p.x = rne_bf16(vl.x) | (rne_bf16(vl.y) << 16);
    p.y = rne_bf16(vl.z) | (rne_bf16(vl.w) << 16);
    xlh[n * 16 + cg] = p;
    if (cg == 0) deg[n] = 0;
}

// KA: degree histogram over destinations.
__global__ __launch_bounds__(256) void ka_hist(const int* __restrict__ ei,
                                               int* __restrict__ deg) {
    int i = blockIdx.x * blockDim.x + threadIdx.x;
    if (i < N_EDGES) atomicAdd(&deg[ei[N_EDGES + i]], 1);
}

// KB1: per-block exclusive scan of deg -> rowptr (block-local) + block totals.
__global__ __launch_bounds__(256) void kb1_scan(const int* __restrict__ deg,
                                                int* __restrict__ rowptr,
                                                int* __restrict__ bsum) {
    __shared__ int s[256];
    int i = blockIdx.x * 256 + threadIdx.x;
    int v = (i < N_NODES) ? deg[i] : 0;
    s[threadIdx.x] = v;
    __syncthreads();
#pragma unroll
    for (int off = 1; off < 256; off <<= 1) {
        int t = (threadIdx.x >= off) ? s[threadIdx.x - off] : 0;
        __syncthreads();
        s[threadIdx.x] += t;
        __syncthreads();
    }
    if (i < N_NODES) rowptr[i] = s[threadIdx.x] - v;  // exclusive
    if (threadIdx.x == 255) bsum[blockIdx.x] = s[255];
}

// KB2: single-block exclusive scan of block totals (NB_SCAN=391 <= 512).
__global__ __launch_bounds__(512) void kb2_scan(int* __restrict__ bsum) {
    __shared__ int s[512];
    int v = (threadIdx.x < NB_SCAN) ? bsum[threadIdx.x] : 0;
    s[threadIdx.x] = v;
    __syncthreads();
#pragma unroll
    for (int off = 1; off < 512; off <<= 1) {
        int t = (threadIdx.x >= off) ? s[threadIdx.x - off] : 0;
        __syncthreads();
        s[threadIdx.x] += t;
        __syncthreads();
    }
    if (threadIdx.x < NB_SCAN) bsum[threadIdx.x] = s[threadIdx.x] - v;
}

// KB3: add block offsets; init cursor = rowptr.
__global__ __launch_bounds__(256) void kb3_fix(const int* __restrict__ bsum,
                                               int* __restrict__ rowptr,
                                               int* __restrict__ cursor) {
    int i = blockIdx.x * 256 + threadIdx.x;
    if (i < N_NODES) {
        int r = rowptr[i] + bsum[blockIdx.x];
        rowptr[i] = r;
        cursor[i] = r;
    }
    if (i == 0) rowptr[N_NODES] = N_EDGES;
}

// KC: scatter edge sources into dst-grouped order.
__global__ __launch_bounds__(256) void kc_scatter(const int* __restrict__ ei,
                                                  int* __restrict__ cursor,
                                                  int* __restrict__ esrc) {
    int i = blockIdx.x * blockDim.x + threadIdx.x;
    if (i >= N_EDGES) return;
    int src = ei[i];
    int dst = ei[N_EDGES + i];
    int slot = atomicAdd(&cursor[dst], 1);
    esrc[slot] = src;
}

// KD: fused node aggregation + LN stats + graph pooling.
// One WAVE per node-chunk; within the wave 4 edge-slots x 16 lanes, 4 ch/lane.
// Each iteration: 4 edges gathered in one instruction. Slot-private num/den
// partials (softmax linearity), combined once per node via 2 cross-slot shfls.
__global__ __launch_bounds__(256, 8) void kd_node_agg(
    const int* __restrict__ rowptr, const int* __restrict__ esrc,
    const uint2* __restrict__ xlh, const float4* __restrict__ xr4,
    const float* __restrict__ att, const float* __restrict__ cb,
    const int* __restrict__ batch,
    float* __restrict__ gsum, float* __restrict__ gcnt,
    double* __restrict__ stats) {
    __shared__ float sS[4], sQ[4];
    int w = threadIdx.x >> 6;             // wave-in-block 0..3
    int lane = threadIdx.x & 63;
    int slot = lane >> 4;                 // 0..3: edge slot
    int cg = lane & 15;                   // channel group (4 ch)
    int wid = blockIdx.x * 4 + w;
    int n0 = wid * KD_CHUNK;
    int n1 = min(n0 + KD_CHUNK, N_NODES);

    float4 av = ((const float4*)att)[cg];
    float4 cv = ((const float4*)cb)[cg];

    float lsum = 0.f, lsq = 0.f;
    float gacc0 = 0.f, gacc1 = 0.f, gacc2 = 0.f, gacc3 = 0.f;
    float runcnt = 0.f;
    int cur_g = -1;

    for (int n = n0; n < n1; ++n) {
        int beg = rowptr[n], end = rowptr[n + 1];
        float4 xr = xr4[n * 16 + cg];
        float num0 = 0.f, num1 = 0.f, num2 = 0.f, num3 = 0.f, den = 0.f;
        // pipelined: prefetch next quad's row while computing current
        int j = beg + slot;
        uint2 p = make_uint2(0, 0);
        if (j < end) p = xlh[esrc[j] * 16 + cg];
        for (int j0 = beg; j0 < end; j0 += 4) {
            uint2 pc = p;
            bool vc = (j0 + slot) < end;
            int jn = j0 + 4 + slot;
            if (jn < end) p = xlh[esrc[jn] * 16 + cg];
            float f0 = __uint_as_float(pc.x << 16);
            float f1 = __uint_as_float(pc.x & 0xffff0000u);
            float f2 = __uint_as_float(pc.y << 16);
            float f3 = __uint_as_float(pc.y & 0xffff0000u);
            float h0 = f0 + xr.x, h1 = f1 + xr.y, h2 = f2 + xr.z, h3 = f3 + xr.w;
            float l0 = fmaxf(h0, 0.f) + 0.2f * fminf(h0, 0.f);
            float l1 = fmaxf(h1, 0.f) + 0.2f * fminf(h1, 0.f);
            float l2 = fmaxf(h2, 0.f) + 0.2f * fminf(h2, 0.f);
            float l3 = fmaxf(h3, 0.f) + 0.2f * fminf(h3, 0.f);
            float part = l0 * av.x + l1 * av.y + l2 * av.z + l3 * av.w;
            float e = groupReduceSum16(part);   // within-slot 16-lane reduce
            float ex = vc ? __expf(e) : 0.f;
            den += ex;
            num0 += ex * f0; num1 += ex * f1; num2 += ex * f2; num3 += ex * f3;
        }
        // combine the 4 slot-partials (xor 16 then 32 -> all lanes hold totals)
#pragma unroll
        for (int off = 16; off <= 32; off <<= 1) {
            num0 += __shfl_xor(num0, off, 64);
            num1 += __shfl_xor(num1, off, 64);
            num2 += __shfl_xor(num2, off, 64);
            num3 += __shfl_xor(num3, off, 64);
            den += __shfl_xor(den, off, 64);
        }
        float inv = (den > 0.f) ? (1.f / den) : 0.f;
        float v0 = fmaxf(num0 * inv + cv.x, 0.f);
        float v1 = fmaxf(num1 * inv + cv.y, 0.f);
        float v2 = fmaxf(num2 * inv + cv.z, 0.f);
        float v3 = fmaxf(num3 * inv + cv.w, 0.f);
        if (slot == 0) {   // values replicated across slots; count once
            lsum += v0 + v1 + v2 + v3;
            lsq += v0 * v0 + v1 * v1 + v2 * v2 + v3 * v3;
            int g = batch[n];
            if (g != cur_g) {
                if (cur_g >= 0) {
                    unsafeAtomicAdd(&gsum[cur_g * HID + cg * 4 + 0], gacc0);
                    unsafeAtomicAdd(&gsum[cur_g * HID + cg * 4 + 1], gacc1);
                    unsafeAtomicAdd(&gsum[cur_g * HID + cg * 4 + 2], gacc2);
                    unsafeAtomicAdd(&gsum[cur_g * HID + cg * 4 + 3], gacc3);
                    if (cg == 0) unsafeAtomicAdd(&gcnt[cur_g], runcnt);
                }
                cur_g = g;
                gacc0 = gacc1 = gacc2 = gacc3 = 0.f;
                runcnt = 0.f;
            }
            gacc0 += v0; gacc1 += v1; gacc2 += v2; gacc3 += v3;
            runcnt += 1.f;
        }
    }
    if (cur_g >= 0) {   // only slot-0 lanes have cur_g >= 0
        unsafeAtomicAdd(&gsum[cur_g * HID + cg * 4 + 0], gacc0);
        unsafeAtomicAdd(&gsum[cur_g * HID + cg * 4 + 1], gacc1);
        unsafeAtomicAdd(&gsum[cur_g * HID + cg * 4 + 2], gacc2);
        unsafeAtomicAdd(&gsum[cur_g * HID + cg * 4 + 3], gacc3);
        if (cg == 0) unsafeAtomicAdd(&gcnt[cur_g], runcnt);
    }
    // LN stats: reduce within slot 0 (other slots hold zeros), then block-level
    lsum = groupReduceSum16(lsum);
    lsq = groupReduceSum16(lsq);
    if (lane == 0) { sS[w] = lsum; sQ[w] = lsq; }
    __syncthreads();
    if (threadIdx.x == 0) {
        double ds = 0.0, dq = 0.0;
#pragma unroll
        for (int i = 0; i < 4; ++i) { ds += (double)sS[i]; dq += (double)sQ[i]; }
        unsafeAtomicAdd(&stats[0], ds);
        unsafeAtomicAdd(&stats[1], dq);
    }
}

// K4: per-graph head.
__global__ __launch_bounds__(64) void k4_head(
    const float* __restrict__ gsum, const float* __restrict__ gcnt,
    const double* __restrict__ stats,
    const float* __restrict__ lnw, const float* __restrict__ lnb,
    const float* __restrict__ linw, const float* __restrict__ linb,
    float* __restrict__ y) {
    int g = blockIdx.x;
    int lane = threadIdx.x;
    double tot = (double)N_NODES * (double)HID;
    double mu = stats[0] / tot;
    double var = stats[1] / tot - mu * mu;
    float rs = rsqrtf((float)var + LN_EPS);
    float cnt = fmaxf(gcnt[g], 1.f);
    float pooled = (gsum[g * HID + lane] / cnt - (float)mu) * rs * lnw[lane] + lnb[lane];
    float t = waveReduceSum(pooled * linw[lane]);
    if (lane == 0) {
        float z = t + linb[0];
        y[g] = 1.f / (1.f + __expf(-z));
    }
}

extern "C" void kernel_launch(void* const* d_in, const int* in_sizes, int n_in,
                              void* d_out, int out_size, void* d_ws, size_t ws_size,
                              hipStream_t stream) {
    const float* x = (const float*)d_in[0];
    const int* ei = (const int*)d_in[1];
    const int* batch = (const int*)d_in[2];
    const float* Wl = (const float*)d_in[3];
    const float* bl = (const float*)d_in[4];
    const float* Wr = (const float*)d_in[5];
    const float* br = (const float*)d_in[6];
    const float* att = (const float*)d_in[7];
    const float* cb = (const float*)d_in[8];
    const float* lnw = (const float*)d_in[9];
    const float* lnb = (const float*)d_in[10];
    const float* linw = (const float*)d_in[11];
    const float* linb = (const float*)d_in[12];
    float* y = (float*)d_out;

    char* ws = (char*)d_ws;
    float4* xr4 = (float4*)ws;                                   // N*16 float4
    uint2* xlh = (uint2*)(ws + (size_t)N_NODES * 16 * 16);       // N*16 uint2
    float* gsum = (float*)((char*)xlh + (size_t)N_NODES * 16 * 8);
    float* gcnt = gsum + N_GRAPHS * HID;
    double* stats = (double*)(gcnt + N_GRAPHS);
    int* rowptr = (int*)(stats + 2);
    int* cursor = rowptr + (N_NODES + 1);
    int* deg = cursor + N_NODES;
    int* bsum = deg + N_NODES;
    int* esrc = bsum + 512;

    k0_transform<<<(N_NODES * 16 + 255) / 256, 256, 0, stream>>>(
        x, Wl, bl, Wr, br, xlh, xr4, deg, gsum, gcnt, stats);
    ka_hist<<<(N_EDGES + 255) / 256, 256, 0, stream>>>(ei, deg);
    kb1_scan<<<NB_SCAN, 256, 0, stream>>>(deg, rowptr, bsum);
    kb2_scan<<<1, 512, 0, stream>>>(bsum);
    kb3_fix<<<NB_SCAN, 256, 0, stream>>>(bsum, rowptr, cursor);
    kc_scatter<<<(N_EDGES + 255) / 256, 256, 0, stream>>>(ei, cursor, esrc);
    kd_node_agg<<<KD_BLOCKS, 256, 0, stream>>>(
        rowptr, esrc, xlh, xr4, att, cb, batch, gsum, gcnt, stats);
    k4_head<<<N_GRAPHS, 64, 0, stream>>>(gsum, gcnt, stats, lnw, lnb, linw, linb, y);
}

// Round 6
// 348.098 us; speedup vs baseline: 2.5426x; 1.1553x over previous
//
#include <hip/hip_runtime.h>
#include <math.h>

#define N_NODES 100000
#define N_EDGES 1600000
#define N_GRAPHS 64
#define HID 64
#define LN_EPS 1e-5f
#define NB_SCAN ((N_NODES + 255) / 256)   // 391 scan blocks
#define KD_BLOCKS 2048
#define KD_WAVES (KD_BLOCKS * 4)          // 8192 waves, one node-chunk per wave
#define KD_CHUNK ((N_NODES + KD_WAVES - 1) / KD_WAVES)  // 13 contiguous nodes/wave

__device__ __forceinline__ float waveReduceSum(float v) {
#pragma unroll
    for (int off = 32; off > 0; off >>= 1)
        v += __shfl_xor(v, off, 64);
    return v;
}

__device__ __forceinline__ float groupReduceSum16(float v) {
#pragma unroll
    for (int off = 8; off > 0; off >>= 1)
        v += __shfl_xor(v, off, 64);
    return v;
}

__device__ __forceinline__ unsigned rne_bf16(float f) {
    unsigned u = __float_as_uint(f);
    return (u + 0x7fffu + ((u >> 16) & 1u)) >> 16;
}

// K0: per-node transforms. One thread per (node, channel-group).
// xr stored f32 (float4/lane), xl stored packed bf16 (uint2/lane). + ws init.
__global__ __launch_bounds__(256) void k0_transform(
    const float* __restrict__ x,
    const float* __restrict__ Wl, const float* __restrict__ bl,
    const float* __restrict__ Wr, const float* __restrict__ br,
    uint2* __restrict__ xlh, float4* __restrict__ xr4,
    int* __restrict__ deg,
    float* __restrict__ gsum, float* __restrict__ gcnt,
    double* __restrict__ stats) {
    if (blockIdx.x == 0) {
        for (int i = threadIdx.x; i < N_GRAPHS * HID; i += blockDim.x) gsum[i] = 0.f;
        if (threadIdx.x < N_GRAPHS) gcnt[threadIdx.x] = 0.f;
        if (threadIdx.x < 2) stats[threadIdx.x] = 0.0;
    }
    int t = blockIdx.x * blockDim.x + threadIdx.x;
    int n = t >> 4;
    int cg = t & 15;
    if (n >= N_NODES) return;
    float4 xv = ((const float4*)x)[n];
    float4 w0 = ((const float4*)Wl)[0 * 16 + cg];
    float4 w1 = ((const float4*)Wl)[1 * 16 + cg];
    float4 w2 = ((const float4*)Wl)[2 * 16 + cg];
    float4 w3 = ((const float4*)Wl)[3 * 16 + cg];
    float4 bv = ((const float4*)bl)[cg];
    float4 vl;
    vl.x = bv.x + xv.x * w0.x + xv.y * w1.x + xv.z * w2.x + xv.w * w3.x;
    vl.y = bv.y + xv.x * w0.y + xv.y * w1.y + xv.z * w2.y + xv.w * w3.y;
    vl.z = bv.z + xv.x * w0.z + xv.y * w1.z + xv.z * w2.z + xv.w * w3.z;
    vl.w = bv.w + xv.x * w0.w + xv.y * w1.w + xv.z * w2.w + xv.w * w3.w;
    w0 = ((const float4*)Wr)[0 * 16 + cg];
    w1 = ((const float4*)Wr)[1 * 16 + cg];
    w2 = ((const float4*)Wr)[2 * 16 + cg];
    w3 = ((const float4*)Wr)[3 * 16 + cg];
    bv = ((const float4*)br)[cg];
    float4 vr;
    vr.x = bv.x + xv.x * w0.x + xv.y * w1.x + xv.z * w2.x + xv.w * w3.x;
    vr.y = bv.y + xv.x * w0.y + xv.y * w1.y + xv.z * w2.y + xv.w * w3.y;
    vr.z = bv.z + xv.x * w0.z + xv.y * w1.z + xv.z * w2.z + xv.w * w3.z;
    vr.w = bv.w + xv.x * w0.w + xv.y * w1.w + xv.z * w2.w + xv.w * w3.w;
    xr4[n * 16 + cg] = vr;
    uint2 p;
    p.x = rne_bf16(vl.x) | (rne_bf16(vl.y) << 16);
    p.y = rne_bf16(vl.z) | (rne_bf16(vl.w) << 16);
    xlh[n * 16 + cg] = p;
    if (cg == 0) deg[n] = 0;
}

// KA: degree histogram over destinations.
__global__ __launch_bounds__(256) void ka_hist(const int* __restrict__ ei,
                                               int* __restrict__ deg) {
    int i = blockIdx.x * blockDim.x + threadIdx.x;
    if (i < N_EDGES) atomicAdd(&deg[ei[N_EDGES + i]], 1);
}

// KB1: per-block exclusive scan of deg -> rowptr (block-local) + block totals.
__global__ __launch_bounds__(256) void kb1_scan(const int* __restrict__ deg,
                                                int* __restrict__ rowptr,
                                                int* __restrict__ bsum) {
    __shared__ int s[256];
    int i = blockIdx.x * 256 + threadIdx.x;
    int v = (i < N_NODES) ? deg[i] : 0;
    s[threadIdx.x] = v;
    __syncthreads();
#pragma unroll
    for (int off = 1; off < 256; off <<= 1) {
        int t = (threadIdx.x >= off) ? s[threadIdx.x - off] : 0;
        __syncthreads();
        s[threadIdx.x] += t;
        __syncthreads();
    }
    if (i < N_NODES) rowptr[i] = s[threadIdx.x] - v;  // exclusive
    if (threadIdx.x == 255) bsum[blockIdx.x] = s[255];
}

// KB2: single-block exclusive scan of block totals (NB_SCAN=391 <= 512).
__global__ __launch_bounds__(512) void kb2_scan(int* __restrict__ bsum) {
    __shared__ int s[512];
    int v = (threadIdx.x < NB_SCAN) ? bsum[threadIdx.x] : 0;
    s[threadIdx.x] = v;
    __syncthreads();
#pragma unroll
    for (int off = 1; off < 512; off <<= 1) {
        int t = (threadIdx.x >= off) ? s[threadIdx.x - off] : 0;
        __syncthreads();
        s[threadIdx.x] += t;
        __syncthreads();
    }
    if (threadIdx.x < NB_SCAN) bsum[threadIdx.x] = s[threadIdx.x] - v;
}

// KB3: add block offsets; init cursor = rowptr.
__global__ __launch_bounds__(256) void kb3_fix(const int* __restrict__ bsum,
                                               int* __restrict__ rowptr,
                                               int* __restrict__ cursor) {
    int i = blockIdx.x * 256 + threadIdx.x;
    if (i < N_NODES) {
        int r = rowptr[i] + bsum[blockIdx.x];
        rowptr[i] = r;
        cursor[i] = r;
    }
    if (i == 0) rowptr[N_NODES] = N_EDGES;
}

// KC: XCD-partitioned scatter. Each XCD (blockIdx%8 round-robin heuristic)
// owns a contiguous 12.5k slice of dst space; its 64 blocks scan the WHOLE
// edge list (int4 dst reads) and scatter only owned edges. All writes to an
// esrc line then come from one XCD -> merge in its L2 -> ~6.4MB writeback
// instead of 1.6M full-line (102MB) writebacks. Correct under any mapping.
__global__ __launch_bounds__(256) void kc_scatter(const int* __restrict__ ei,
                                                  int* __restrict__ cursor,
                                                  int* __restrict__ esrc) {
    int xcd = blockIdx.x & 7;
    int sub = blockIdx.x >> 3;                 // 0..63
    int lo = xcd * (N_NODES / 8);
    int hi = lo + (N_NODES / 8);
    int tid = sub * 256 + (int)threadIdx.x;    // 0..16383 within XCD group
    for (int q = tid; q < N_EDGES / 4; q += 64 * 256) {
        int4 d4 = ((const int4*)(ei + N_EDGES))[q];
        int i0 = q * 4;
        if (d4.x >= lo && d4.x < hi) esrc[atomicAdd(&cursor[d4.x], 1)] = ei[i0 + 0];
        if (d4.y >= lo && d4.y < hi) esrc[atomicAdd(&cursor[d4.y], 1)] = ei[i0 + 1];
        if (d4.z >= lo && d4.z < hi) esrc[atomicAdd(&cursor[d4.z], 1)] = ei[i0 + 2];
        if (d4.w >= lo && d4.w < hi) esrc[atomicAdd(&cursor[d4.w], 1)] = ei[i0 + 3];
    }
}

// KD: fused node aggregation + LN stats + graph pooling.
// One WAVE per node-chunk; within the wave 4 edge-slots x 16 lanes, 4 ch/lane.
__global__ __launch_bounds__(256, 8) void kd_node_agg(
    const int* __restrict__ rowptr, const int* __restrict__ esrc,
    const uint2* __restrict__ xlh, const float4* __restrict__ xr4,
    const float* __restrict__ att, const float* __restrict__ cb,
    const int* __restrict__ batch,
    float* __restrict__ gsum, float* __restrict__ gcnt,
    double* __restrict__ stats) {
    __shared__ float sS[4], sQ[4];
    int w = threadIdx.x >> 6;             // wave-in-block 0..3
    int lane = threadIdx.x & 63;
    int slot = lane >> 4;                 // 0..3: edge slot
    int cg = lane & 15;                   // channel group (4 ch)
    int wid = blockIdx.x * 4 + w;
    int n0 = wid * KD_CHUNK;
    int n1 = min(n0 + KD_CHUNK, N_NODES);

    float4 av = ((const float4*)att)[cg];
    float4 cv = ((const float4*)cb)[cg];

    float lsum = 0.f, lsq = 0.f;
    float gacc0 = 0.f, gacc1 = 0.f, gacc2 = 0.f, gacc3 = 0.f;
    float runcnt = 0.f;
    int cur_g = -1;

    for (int n = n0; n < n1; ++n) {
        int beg = rowptr[n], end = rowptr[n + 1];
        float4 xr = xr4[n * 16 + cg];
        float num0 = 0.f, num1 = 0.f, num2 = 0.f, num3 = 0.f, den = 0.f;
        int j = beg + slot;
        uint2 p = make_uint2(0, 0);
        if (j < end) p = xlh[esrc[j] * 16 + cg];
        for (int j0 = beg; j0 < end; j0 += 4) {
            uint2 pc = p;
            bool vc = (j0 + slot) < end;
            int jn = j0 + 4 + slot;
            if (jn < end) p = xlh[esrc[jn] * 16 + cg];
            float f0 = __uint_as_float(pc.x << 16);
            float f1 = __uint_as_float(pc.x & 0xffff0000u);
            float f2 = __uint_as_float(pc.y << 16);
            float f3 = __uint_as_float(pc.y & 0xffff0000u);
            float h0 = f0 + xr.x, h1 = f1 + xr.y, h2 = f2 + xr.z, h3 = f3 + xr.w;
            float l0 = fmaxf(h0, 0.f) + 0.2f * fminf(h0, 0.f);
            float l1 = fmaxf(h1, 0.f) + 0.2f * fminf(h1, 0.f);
            float l2 = fmaxf(h2, 0.f) + 0.2f * fminf(h2, 0.f);
            float l3 = fmaxf(h3, 0.f) + 0.2f * fminf(h3, 0.f);
            float part = l0 * av.x + l1 * av.y + l2 * av.z + l3 * av.w;
            float e = groupReduceSum16(part);   // within-slot 16-lane reduce
            float ex = vc ? __expf(e) : 0.f;
            den += ex;
            num0 += ex * f0; num1 += ex * f1; num2 += ex * f2; num3 += ex * f3;
        }
#pragma unroll
        for (int off = 16; off <= 32; off <<= 1) {
            num0 += __shfl_xor(num0, off, 64);
            num1 += __shfl_xor(num1, off, 64);
            num2 += __shfl_xor(num2, off, 64);
            num3 += __shfl_xor(num3, off, 64);
            den += __shfl_xor(den, off, 64);
        }
        float inv = (den > 0.f) ? (1.f / den) : 0.f;
        float v0 = fmaxf(num0 * inv + cv.x, 0.f);
        float v1 = fmaxf(num1 * inv + cv.y, 0.f);
        float v2 = fmaxf(num2 * inv + cv.z, 0.f);
        float v3 = fmaxf(num3 * inv + cv.w, 0.f);
        if (slot == 0) {   // values replicated across slots; count once
            lsum += v0 + v1 + v2 + v3;
            lsq += v0 * v0 + v1 * v1 + v2 * v2 + v3 * v3;
            int g = batch[n];
            if (g != cur_g) {
                if (cur_g >= 0) {
                    unsafeAtomicAdd(&gsum[cur_g * HID + cg * 4 + 0], gacc0);
                    unsafeAtomicAdd(&gsum[cur_g * HID + cg * 4 + 1], gacc1);
                    unsafeAtomicAdd(&gsum[cur_g * HID + cg * 4 + 2], gacc2);
                    unsafeAtomicAdd(&gsum[cur_g * HID + cg * 4 + 3], gacc3);
                    if (cg == 0) unsafeAtomicAdd(&gcnt[cur_g], runcnt);
                }
                cur_g = g;
                gacc0 = gacc1 = gacc2 = gacc3 = 0.f;
                runcnt = 0.f;
            }
            gacc0 += v0; gacc1 += v1; gacc2 += v2; gacc3 += v3;
            runcnt += 1.f;
        }
    }
    if (cur_g >= 0) {   // only slot-0 lanes have cur_g >= 0
        unsafeAtomicAdd(&gsum[cur_g * HID + cg * 4 + 0], gacc0);
        unsafeAtomicAdd(&gsum[cur_g * HID + cg * 4 + 1], gacc1);
        unsafeAtomicAdd(&gsum[cur_g * HID + cg * 4 + 2], gacc2);
        unsafeAtomicAdd(&gsum[cur_g * HID + cg * 4 + 3], gacc3);
        if (cg == 0) unsafeAtomicAdd(&gcnt[cur_g], runcnt);
    }
    lsum = groupReduceSum16(lsum);
    lsq = groupReduceSum16(lsq);
    if (lane == 0) { sS[w] = lsum; sQ[w] = lsq; }
    __syncthreads();
    if (threadIdx.x == 0) {
        double ds = 0.0, dq = 0.0;
#pragma unroll
        for (int i = 0; i < 4; ++i) { ds += (double)sS[i]; dq += (double)sQ[i]; }
        unsafeAtomicAdd(&stats[0], ds);
        unsafeAtomicAdd(&stats[1], dq);
    }
}

// K4: per-graph head.
__global__ __launch_bounds__(64) void k4_head(
    const float* __restrict__ gsum, const float* __restrict__ gcnt,
    const double* __restrict__ stats,
    const float* __restrict__ lnw, const float* __restrict__ lnb,
    const float* __restrict__ linw, const float* __restrict__ linb,
    float* __restrict__ y) {
    int g = blockIdx.x;
    int lane = threadIdx.x;
    double tot = (double)N_NODES * (double)HID;
    double mu = stats[0] / tot;
    double var = stats[1] / tot - mu * mu;
    float rs = rsqrtf((float)var + LN_EPS);
    float cnt = fmaxf(gcnt[g], 1.f);
    float pooled = (gsum[g * HID + lane] / cnt - (float)mu) * rs * lnw[lane] + lnb[lane];
    float t = waveReduceSum(pooled * linw[lane]);
    if (lane == 0) {
        float z = t + linb[0];
        y[g] = 1.f / (1.f + __expf(-z));
    }
}

extern "C" void kernel_launch(void* const* d_in, const int* in_sizes, int n_in,
                              void* d_out, int out_size, void* d_ws, size_t ws_size,
                              hipStream_t stream) {
    const float* x = (const float*)d_in[0];
    const int* ei = (const int*)d_in[1];
    const int* batch = (const int*)d_in[2];
    const float* Wl = (const float*)d_in[3];
    const float* bl = (const float*)d_in[4];
    const float* Wr = (const float*)d_in[5];
    const float* br = (const float*)d_in[6];
    const float* att = (const float*)d_in[7];
    const float* cb = (const float*)d_in[8];
    const float* lnw = (const float*)d_in[9];
    const float* lnb = (const float*)d_in[10];
    const float* linw = (const float*)d_in[11];
    const float* linb = (const float*)d_in[12];
    float* y = (float*)d_out;

    char* ws = (char*)d_ws;
    float4* xr4 = (float4*)ws;                                   // N*16 float4
    uint2* xlh = (uint2*)(ws + (size_t)N_NODES * 16 * 16);       // N*16 uint2
    float* gsum = (float*)((char*)xlh + (size_t)N_NODES * 16 * 8);
    float* gcnt = gsum + N_GRAPHS * HID;
    double* stats = (double*)(gcnt + N_GRAPHS);
    int* rowptr = (int*)(stats + 2);
    int* cursor = rowptr + (N_NODES + 1);
    int* deg = cursor + N_NODES;
    int* bsum = deg + N_NODES;
    int* esrc = bsum + 512;

    k0_transform<<<(N_NODES * 16 + 255) / 256, 256, 0, stream>>>(
        x, Wl, bl, Wr, br, xlh, xr4, deg, gsum, gcnt, stats);
    ka_hist<<<(N_EDGES + 255) / 256, 256, 0, stream>>>(ei, deg);
    kb1_scan<<<NB_SCAN, 256, 0, stream>>>(deg, rowptr, bsum);
    kb2_scan<<<1, 512, 0, stream>>>(bsum);
    kb3_fix<<<NB_SCAN, 256, 0, stream>>>(bsum, rowptr, cursor);
    kc_scatter<<<512, 256, 0, stream>>>(ei, cursor, esrc);
    kd_node_agg<<<KD_BLOCKS, 256, 0, stream>>>(
        rowptr, esrc, xlh, xr4, att, cb, batch, gsum, gcnt, stats);
    k4_head<<<N_GRAPHS, 64, 0, stream>>>(gsum, gcnt, stats, lnw, lnb, linw, linb, y);
}